// Round 2
// baseline (717.672 us; speedup 1.0000x reference)
//
#include <hip/hip_runtime.h>
#include <math.h>

#define ANUM 3
#define BNUM 32
#define MNUM 16
#define NBIN 2048
#define CAP  2048
#define N0 76800
#define N1 19200
#define N2 4800
#define ZLEN (96*NBIN + 480 + 96 + 96 + 96 + 3)

__device__ __forceinline__ float wred(float v){
  #pragma unroll
  for (int off=32; off; off>>=1) v += __shfl_down(v, off, 64);
  return v;
}

__global__ __launch_bounds__(256) void kzero(float* z){
  int i = blockIdx.x*256 + threadIdx.x;
  if (i < ZLEN) z[i] = 0.f;
}

// One thread per pixel, 3 anchors per thread. All 3 scales in one launch.
__global__ __launch_bounds__(256) void k1(
    const float* __restrict__ p0, const float* __restrict__ p1, const float* __restrict__ p2,
    const float* __restrict__ boxes, const int* __restrict__ labels,
    float* __restrict__ negvals, int* __restrict__ hist, float* __restrict__ acc)
{
  const int b = blockIdx.y;
  const int bx = blockIdx.x;
  int s, lb, W, HW; const float* __restrict__ pred; size_t segbase;
  if (bx < 100)      { s=0; lb=bx;     W=160; HW=25600; pred=p0; segbase=(size_t)b*N0; }
  else if (bx < 125) { s=1; lb=bx-100; W=80;  HW=6400;  pred=p1; segbase=(size_t)BNUM*N0 + (size_t)b*N1; }
  else               { s=2; lb=bx-125; W=40;  HW=1600;  pred=p2; segbase=(size_t)BNUM*(N0+N1) + (size_t)b*N2; }
  const int g = s*BNUM + b;

  __shared__ float sraw[64];
  __shared__ float scor[16][5];
  __shared__ int   slab[16];
  __shared__ int   shist[NBIN];

  #pragma unroll
  for (int j=0;j<NBIN/256;j++) shist[threadIdx.x + j*256] = 0;
  if (threadIdx.x < 64) sraw[threadIdx.x] = boxes[b*64 + threadIdx.x];
  else if (threadIdx.x < 80) slab[threadIdx.x-64] = labels[b*16 + threadIdx.x - 64];
  __syncthreads();
  if (threadIdx.x < 16){
    float bcx=sraw[4*threadIdx.x], bcy=sraw[4*threadIdx.x+1];
    float bw =sraw[4*threadIdx.x+2], bh=sraw[4*threadIdx.x+3];
    float x0=bcx-bw*0.5f, y0=bcy-bh*0.5f, x1=bcx+bw*0.5f, y1=bcy+bh*0.5f;
    scor[threadIdx.x][0]=x0; scor[threadIdx.x][1]=y0;
    scor[threadIdx.x][2]=x1; scor[threadIdx.x][3]=y1;
    scor[threadIdx.x][4]=(x1-x0)*(y1-y0);
  }
  __syncthreads();

  const int pix = lb*256 + threadIdx.x;
  float f_pos=0.f, f_neg=0.f, f_obj=0.f, f_ce=0.f, f_sl1=0.f;

  if (pix < HW){
    const int h = pix / W;
    const int w = pix - h*W;
    const float fw = (float)W;  // H == W for all scales
    const float cx = ((float)w + 0.5f)/fw;
    const float cy = ((float)h + 0.5f)/fw;
    const float* pb = pred + (size_t)b*24*HW;

    #pragma unroll
    for (int a=0;a<ANUM;a++){
      const float sz = (a==0)?0.08f:((a==1)?0.16f:0.28f);
      const float hs = sz*0.5f;
      const float ax0=cx-hs, ay0=cy-hs, ax1=cx+hs, ay1=cy+hs;
      const float areaA=(ax1-ax0)*(ay1-ay0);
      float best=-1.f; int midx=0;
      #pragma unroll
      for (int m=0;m<16;m++){
        float iw=fminf(ax1,scor[m][2])-fmaxf(ax0,scor[m][0]);
        float ih=fminf(ay1,scor[m][3])-fmaxf(ay0,scor[m][1]);
        iw=fmaxf(iw,0.f); ih=fmaxf(ih,0.f);
        float inter=iw*ih;
        float iou=inter/(areaA+scor[m][4]-inter+1e-9f);
        if (iou>best){best=iou; midx=m;}
      }
      const bool pos = best>=0.5f;
      const bool neg = best<0.4f;
      const float obj = pb[(a*8+4)*HW + pix];
      const float sp = log1pf(expf(-fabsf(obj)));
      const float obj_all = fmaxf(obj,0.f) - (pos?obj:0.f) + sp;
      negvals[segbase + a*HW + pix] = neg ? obj_all : -1.f;
      if (neg){
        f_neg += 1.f;
        atomicAdd(&shist[__float_as_uint(obj_all)>>20], 1);
      } else if (pos){
        f_pos += 1.f; f_obj += obj_all;
        float c0=pb[(a*8+5)*HW+pix], c1=pb[(a*8+6)*HW+pix], c2=pb[(a*8+7)*HW+pix];
        float mx=fmaxf(c0,fmaxf(c1,c2));
        float lse=mx+logf(expf(c0-mx)+expf(c1-mx)+expf(c2-mx));
        int ct=slab[midx]-1; ct = ct<0?0:(ct>2?2:ct);
        float csel=(ct==0)?c0:((ct==1)?c1:c2);
        f_ce += lse-csel;
        float mcx=sraw[4*midx],mcy=sraw[4*midx+1],mw=sraw[4*midx+2],mh=sraw[4*midx+3];
        float t0=(mcx-cx)/sz, t1=(mcy-cy)/sz, t2=logf(mw/sz), t3=logf(mh/sz);
        float l0=pb[(a*8+0)*HW+pix], l1=pb[(a*8+1)*HW+pix];
        float l2=pb[(a*8+2)*HW+pix], l3=pb[(a*8+3)*HW+pix];
        float d, ssm=0.f;
        d=fabsf(l0-t0); ssm += (d<1.f)?(0.5f*d*d):(d-0.5f);
        d=fabsf(l1-t1); ssm += (d<1.f)?(0.5f*d*d):(d-0.5f);
        d=fabsf(l2-t2); ssm += (d<1.f)?(0.5f*d*d):(d-0.5f);
        d=fabsf(l3-t3); ssm += (d<1.f)?(0.5f*d*d):(d-0.5f);
        f_sl1 += ssm;
      }
    }
  }

  __syncthreads();
  // flush LDS hist (sparse)
  #pragma unroll
  for (int j=0;j<NBIN/256;j++){
    int bin = threadIdx.x + j*256;
    int c = shist[bin];
    if (c) atomicAdd(&hist[g*NBIN + bin], c);
  }

  __shared__ float red[5][4];
  const int lane = threadIdx.x & 63, wv = threadIdx.x >> 6;
  float vals[5] = {f_pos, f_neg, f_obj, f_ce, f_sl1};
  #pragma unroll
  for (int q=0;q<5;q++){
    float r = wred(vals[q]);
    if (lane==0) red[q][wv] = r;
  }
  __syncthreads();
  if (threadIdx.x==0){
    float* ag = acc + g*5;
    #pragma unroll
    for (int q=0;q<5;q++){
      float t = red[q][0]+red[q][1]+red[q][2]+red[q][3];
      if (t != 0.f) atomicAdd(&ag[q], t);
    }
  }
}

// 96 blocks: suffix-scan 2048 bins -> prefix bin + within-bin rank r
__global__ __launch_bounds__(256) void kfindbin(const int* __restrict__ hist,
                                                const float* __restrict__ acc,
                                                int* __restrict__ binr)
{
  const int g = blockIdx.x;
  const int t = threadIdx.x;
  const int4* h4 = (const int4*)(hist + g*NBIN);
  int4 v0 = h4[t*2+0], v1 = h4[t*2+1];
  int lv[8] = {v0.x,v0.y,v0.z,v0.w, v1.x,v1.y,v1.z,v1.w};
  int sum = 0;
  #pragma unroll
  for (int j=0;j<8;j++) sum += lv[j];

  __shared__ int sa[256], sb[256];
  sa[t] = sum; __syncthreads();
  int* src = sa; int* dst = sb;
  #pragma unroll
  for (int st=1; st<256; st<<=1){
    int v = src[t] + ((t+st<256)? src[t+st] : 0);
    dst[t] = v; __syncthreads();
    int* tmp = src; src = dst; dst = tmp;
  }
  // src[t] = inclusive suffix sum over thread chunks t..255

  const float nposf = acc[g*5+0], availf = acc[g*5+1];
  const int npos = (int)(nposf+0.5f), avail = (int)(availf+0.5f);
  const int k = (npos==0) ? (avail<100?avail:100) : (3*npos<avail?3*npos:avail);
  if (t==0 && k<=0){ binr[g*2]=NBIN; binr[g*2+1]=0; }
  if (k>0){
    int above = (t<255) ? src[t+1] : 0;
    if (above < k && above + sum >= k){
      int cum = above;
      #pragma unroll
      for (int j=7;j>=0;j--){
        int c = lv[j];
        if (cum + c >= k){ binr[g*2] = t*8 + j; binr[g*2+1] = k - cum; break; }
        cum += c;
      }
    }
  }
}

// fully-parallel pass: sum/count above prefix bin; collect prefix-bin candidates
__global__ __launch_bounds__(256) void kpassA(
    const float* __restrict__ negvals, const int* __restrict__ binr,
    float* __restrict__ asum, float* __restrict__ acnt,
    int* __restrict__ candcnt, float* __restrict__ cand)
{
  const int b = blockIdx.y;
  const int bx = blockIdx.x;
  int s, lb, Nq; size_t segbase;
  if (bx < 75)      { s=0; lb=bx;    Nq=N0/4; segbase=(size_t)b*N0; }
  else if (bx < 94) { s=1; lb=bx-75; Nq=N1/4; segbase=(size_t)BNUM*N0 + (size_t)b*N1; }
  else              { s=2; lb=bx-94; Nq=N2/4; segbase=(size_t)BNUM*(N0+N1) + (size_t)b*N2; }
  const int g = s*BNUM + b;
  const int pbin = binr[g*2];
  const int i = lb*256 + threadIdx.x;
  float sum=0.f, cnt=0.f;
  if (i < Nq){
    const float4 v4 = ((const float4*)(negvals+segbase))[i];
    float vv[4] = {v4.x, v4.y, v4.z, v4.w};
    #pragma unroll
    for (int j=0;j<4;j++){
      float v = vv[j];
      if (v >= 0.f){
        int vb = (int)(__float_as_uint(v)>>20);
        if (vb > pbin){ sum += v; cnt += 1.f; }
        else if (vb == pbin){
          int idx = atomicAdd(&candcnt[g], 1);
          if (idx < CAP) cand[g*CAP + idx] = v;
        }
      }
    }
  }
  __shared__ float red[2][4];
  const int lane = threadIdx.x & 63, wv = threadIdx.x >> 6;
  float r0 = wred(sum), r1 = wred(cnt);
  if (lane==0){ red[0][wv]=r0; red[1][wv]=r1; }
  __syncthreads();
  if (threadIdx.x==0){
    float ts = red[0][0]+red[0][1]+red[0][2]+red[0][3];
    float tc = red[1][0]+red[1][1]+red[1][2]+red[1][3];
    if (ts != 0.f) atomicAdd(&asum[g], ts);
    if (tc != 0.f) atomicAdd(&acnt[g], tc);
  }
}

// 96 blocks: exact rank among candidates -> thr -> per-(b,s) losses
__global__ __launch_bounds__(256) void krank(
    const float* __restrict__ acc, const float* __restrict__ asum, const float* __restrict__ acnt,
    const int* __restrict__ candcnt, const float* __restrict__ cand,
    const int* __restrict__ binr, float* __restrict__ lsum)
{
  const int g = blockIdx.x;
  const int t = threadIdx.x;
  __shared__ float sc[CAP];
  __shared__ float s_thr;
  const float nposf = acc[g*5+0], availf = acc[g*5+1];
  const int npos = (int)(nposf+0.5f), avail = (int)(availf+0.5f);
  const int k = (npos==0) ? (avail<100?avail:100) : (3*npos<avail?3*npos:avail);
  float selS=0.f, selC=0.f;
  if (k > 0){
    const int m = min(candcnt[g], CAP);
    const int r = binr[g*2+1];
    if (t==0) s_thr = INFINITY;
    for (int i=t; i<m; i+=256) sc[i] = cand[g*CAP + i];
    __syncthreads();
    for (int i=t; i<m; i+=256){
      float v = sc[i]; int gt=0, ge=0;
      for (int j=0;j<m;j++){ float w2 = sc[j]; gt += (w2>v)?1:0; ge += (w2>=v)?1:0; }
      if (gt < r && ge >= r) s_thr = v;   // unique by value
    }
    __syncthreads();
    const float thr = s_thr;
    for (int i=t; i<m; i+=256){ float v = sc[i]; if (v >= thr){ selS += v; selC += 1.f; } }
  }
  __shared__ float red[2][4];
  const int lane = t & 63, wv = t >> 6;
  float r0 = wred(selS), r1 = wred(selC);
  if (lane==0){ red[0][wv]=r0; red[1][wv]=r1; }
  __syncthreads();
  if (t==0){
    float ss = red[0][0]+red[0][1]+red[0][2]+red[0][3];
    float ns = red[1][0]+red[1][1]+red[1][2]+red[1][3];
    float totS = asum[g] + ss + acc[g*5+2];
    float totC = acnt[g] + ns + nposf;
    float lo = (totC > 0.f) ? totS/totC : 0.f;
    float lc = (npos > 0) ? acc[g*5+3]/nposf : 0.f;
    float ll = (npos > 0) ? acc[g*5+4]/(nposf*4.f) : 0.f;
    atomicAdd(&lsum[0], lo);
    atomicAdd(&lsum[1], lc);
    atomicAdd(&lsum[2], ll);
  }
}

__global__ __launch_bounds__(64) void kfin(const float* __restrict__ lsum, float* __restrict__ out){
  if (threadIdx.x==0){
    float lo = lsum[0]*(1.f/32.f);
    float lc = lsum[1]*(1.f/32.f);
    float ll = lsum[2]*(1.f/32.f);
    out[0]=lo; out[1]=lc; out[2]=ll; out[3]=lo+lc+ll;
  }
}

extern "C" void kernel_launch(void* const* d_in, const int* in_sizes, int n_in,
                              void* d_out, int out_size, void* d_ws, size_t ws_size,
                              hipStream_t stream)
{
  const float* p0 = (const float*)d_in[0];
  const float* p1 = (const float*)d_in[1];
  const float* p2 = (const float*)d_in[2];
  const float* boxes  = (const float*)d_in[6];
  const int*   labels = (const int*)d_in[7];
  float* out = (float*)d_out;

  float* negvals = (float*)d_ws;                 // 3,225,600 f
  float* zb      = negvals + 3225600;            // zero region start
  int*   hist    = (int*)zb;                     // 96*2048
  float* acc     = zb + 96*NBIN;                 // 480
  float* asum    = acc + 480;                    // 96
  float* acnt    = asum + 96;                    // 96
  int*   candcnt = (int*)(acnt + 96);            // 96
  float* lsum    = acnt + 96 + 96;               // 3
  int*   binr    = (int*)(lsum + 3);             // 192
  float* cand    = lsum + 3 + 192;               // 96*2048

  kzero<<<(ZLEN+255)/256, 256, 0, stream>>>(zb);
  k1<<<dim3(132,32), 256, 0, stream>>>(p0,p1,p2,boxes,labels,negvals,hist,acc);
  kfindbin<<<96, 256, 0, stream>>>(hist, acc, binr);
  kpassA<<<dim3(99,32), 256, 0, stream>>>(negvals, binr, asum, acnt, candcnt, cand);
  krank<<<96, 256, 0, stream>>>(acc, asum, acnt, candcnt, cand, binr, lsum);
  kfin<<<1, 64, 0, stream>>>(lsum, out);
}

// Round 3
// 711.511 us; speedup vs baseline: 1.0087x; 1.0087x over previous
//
#include <hip/hip_runtime.h>
#include <math.h>

#define ANUM 3
#define BNUM 32
#define NBIN 2048
#define CAP  2048
#define N0 76800
#define N1 19200
#define N2 4800
#define ZLEN (96*NBIN + 96)   // hist + candcnt (ints)

__device__ __forceinline__ float wred(float v){
  #pragma unroll
  for (int off=32; off; off>>=1) v += __shfl_down(v, off, 64);
  return v;
}

__global__ __launch_bounds__(256) void kzero(int* z){
  int i = blockIdx.x*256 + threadIdx.x;
  if (i < ZLEN) z[i] = 0;
}

// One thread per pixel, 3 anchors per thread. All 3 scales in one launch.
// Per-block partials via plain stores (NO float atomics).
__global__ __launch_bounds__(256) void k1(
    const float* __restrict__ p0, const float* __restrict__ p1, const float* __restrict__ p2,
    const float* __restrict__ boxes, const int* __restrict__ labels,
    float* __restrict__ negvals, int* __restrict__ hist, float* __restrict__ part)
{
  const int b = blockIdx.y;
  const int bx = blockIdx.x;
  int s, lb, W, HW; const float* __restrict__ pred; size_t segbase;
  if (bx < 100)      { s=0; lb=bx;     W=160; HW=25600; pred=p0; segbase=(size_t)b*N0; }
  else if (bx < 125) { s=1; lb=bx-100; W=80;  HW=6400;  pred=p1; segbase=(size_t)BNUM*N0 + (size_t)b*N1; }
  else               { s=2; lb=bx-125; W=40;  HW=1600;  pred=p2; segbase=(size_t)BNUM*(N0+N1) + (size_t)b*N2; }
  const int g = s*BNUM + b;

  __shared__ float sraw[64];
  __shared__ float scor[16][5];
  __shared__ int   slab[16];
  __shared__ int   shist[NBIN];

  #pragma unroll
  for (int j=0;j<NBIN/256;j++) shist[threadIdx.x + j*256] = 0;
  if (threadIdx.x < 64) sraw[threadIdx.x] = boxes[b*64 + threadIdx.x];
  else if (threadIdx.x < 80) slab[threadIdx.x-64] = labels[b*16 + threadIdx.x - 64];
  __syncthreads();
  if (threadIdx.x < 16){
    float bcx=sraw[4*threadIdx.x], bcy=sraw[4*threadIdx.x+1];
    float bw =sraw[4*threadIdx.x+2], bh=sraw[4*threadIdx.x+3];
    float x0=bcx-bw*0.5f, y0=bcy-bh*0.5f, x1=bcx+bw*0.5f, y1=bcy+bh*0.5f;
    scor[threadIdx.x][0]=x0; scor[threadIdx.x][1]=y0;
    scor[threadIdx.x][2]=x1; scor[threadIdx.x][3]=y1;
    scor[threadIdx.x][4]=(x1-x0)*(y1-y0);
  }
  __syncthreads();

  const int pix = lb*256 + threadIdx.x;
  float f_pos=0.f, f_neg=0.f, f_obj=0.f, f_ce=0.f, f_sl1=0.f;

  if (pix < HW){
    const int h = pix / W;
    const int w = pix - h*W;
    const float fw = (float)W;  // H == W for all scales
    const float cx = ((float)w + 0.5f)/fw;
    const float cy = ((float)h + 0.5f)/fw;
    const float* pb = pred + (size_t)b*24*HW;

    #pragma unroll
    for (int a=0;a<ANUM;a++){
      const float sz = (a==0)?0.08f:((a==1)?0.16f:0.28f);
      const float hs = sz*0.5f;
      const float ax0=cx-hs, ay0=cy-hs, ax1=cx+hs, ay1=cy+hs;
      const float areaA=(ax1-ax0)*(ay1-ay0);
      float best=-1.f; int midx=0;
      #pragma unroll
      for (int m=0;m<16;m++){
        float iw=fminf(ax1,scor[m][2])-fmaxf(ax0,scor[m][0]);
        float ih=fminf(ay1,scor[m][3])-fmaxf(ay0,scor[m][1]);
        iw=fmaxf(iw,0.f); ih=fmaxf(ih,0.f);
        float inter=iw*ih;
        float iou=inter/(areaA+scor[m][4]-inter+1e-9f);
        if (iou>best){best=iou; midx=m;}
      }
      const bool pos = best>=0.5f;
      const bool neg = best<0.4f;
      const float obj = pb[(a*8+4)*HW + pix];
      const float sp = log1pf(expf(-fabsf(obj)));
      const float obj_all = fmaxf(obj,0.f) - (pos?obj:0.f) + sp;
      negvals[segbase + a*HW + pix] = neg ? obj_all : -1.f;
      if (neg){
        f_neg += 1.f;
        atomicAdd(&shist[__float_as_uint(obj_all)>>20], 1);   // LDS int atomic: native
      } else if (pos){
        f_pos += 1.f; f_obj += obj_all;
        float c0=pb[(a*8+5)*HW+pix], c1=pb[(a*8+6)*HW+pix], c2=pb[(a*8+7)*HW+pix];
        float mx=fmaxf(c0,fmaxf(c1,c2));
        float lse=mx+logf(expf(c0-mx)+expf(c1-mx)+expf(c2-mx));
        int ct=slab[midx]-1; ct = ct<0?0:(ct>2?2:ct);
        float csel=(ct==0)?c0:((ct==1)?c1:c2);
        f_ce += lse-csel;
        float mcx=sraw[4*midx],mcy=sraw[4*midx+1],mw=sraw[4*midx+2],mh=sraw[4*midx+3];
        float t0=(mcx-cx)/sz, t1=(mcy-cy)/sz, t2=logf(mw/sz), t3=logf(mh/sz);
        float l0=pb[(a*8+0)*HW+pix], l1=pb[(a*8+1)*HW+pix];
        float l2=pb[(a*8+2)*HW+pix], l3=pb[(a*8+3)*HW+pix];
        float d, ssm=0.f;
        d=fabsf(l0-t0); ssm += (d<1.f)?(0.5f*d*d):(d-0.5f);
        d=fabsf(l1-t1); ssm += (d<1.f)?(0.5f*d*d):(d-0.5f);
        d=fabsf(l2-t2); ssm += (d<1.f)?(0.5f*d*d):(d-0.5f);
        d=fabsf(l3-t3); ssm += (d<1.f)?(0.5f*d*d):(d-0.5f);
        f_sl1 += ssm;
      }
    }
  }

  __syncthreads();
  // flush LDS hist (sparse); int atomics are native RMW
  #pragma unroll
  for (int j=0;j<NBIN/256;j++){
    int bin = threadIdx.x + j*256;
    int c = shist[bin];
    if (c) atomicAdd(&hist[g*NBIN + bin], c);
  }

  __shared__ float red[5][4];
  const int lane = threadIdx.x & 63, wv = threadIdx.x >> 6;
  float vals[5] = {f_pos, f_neg, f_obj, f_ce, f_sl1};
  #pragma unroll
  for (int q=0;q<5;q++){
    float r = wred(vals[q]);
    if (lane==0) red[q][wv] = r;
  }
  __syncthreads();
  if (threadIdx.x==0){
    float* pg = part + (size_t)(g*100 + lb)*5;
    #pragma unroll
    for (int q=0;q<5;q++)
      pg[q] = red[q][0]+red[q][1]+red[q][2]+red[q][3];
  }
}

// 96 blocks: reduce k1 partials -> acc; suffix-scan 2048 bins -> prefix bin + rank
__global__ __launch_bounds__(256) void kfindbin(const int* __restrict__ hist,
                                                const float* __restrict__ part,
                                                float* __restrict__ acc,
                                                int* __restrict__ binr)
{
  const int g = blockIdx.x;
  const int t = threadIdx.x;
  const int s = g >> 5;
  const int nb = (s==0)?100:((s==1)?25:7);

  const int4* h4 = (const int4*)(hist + g*NBIN);
  int4 v0 = h4[t*2+0], v1 = h4[t*2+1];
  int lv[8] = {v0.x,v0.y,v0.z,v0.w, v1.x,v1.y,v1.z,v1.w};
  int sum = 0;
  #pragma unroll
  for (int j=0;j<8;j++) sum += lv[j];

  // reduce per-block partials
  float pv[5] = {0.f,0.f,0.f,0.f,0.f};
  if (t < nb){
    const float* pg = part + (size_t)(g*100 + t)*5;
    #pragma unroll
    for (int q=0;q<5;q++) pv[q] = pg[q];
  }
  __shared__ float red[5][4];
  __shared__ int s_k;
  const int lane = t & 63, wv = t >> 6;
  #pragma unroll
  for (int q=0;q<5;q++){
    float r = wred(pv[q]);
    if (lane==0) red[q][wv] = r;
  }
  __syncthreads();
  if (t==0){
    float tot[5];
    #pragma unroll
    for (int q=0;q<5;q++){
      tot[q] = red[q][0]+red[q][1]+red[q][2]+red[q][3];
      acc[g*5+q] = tot[q];
    }
    const int npos = (int)(tot[0]+0.5f), avail = (int)(tot[1]+0.5f);
    int k = (npos==0) ? (avail<100?avail:100) : (3*npos<avail?3*npos:avail);
    s_k = k;
    if (k<=0){ binr[g*2]=NBIN; binr[g*2+1]=0; }
  }
  __syncthreads();
  const int k = s_k;

  __shared__ int sa[256], sb[256];
  sa[t] = sum; __syncthreads();
  int* src = sa; int* dst = sb;
  #pragma unroll
  for (int st=1; st<256; st<<=1){
    int v = src[t] + ((t+st<256)? src[t+st] : 0);
    dst[t] = v; __syncthreads();
    int* tmp = src; src = dst; dst = tmp;
  }
  // src[t] = inclusive suffix sum over thread chunks t..255
  if (k>0){
    int above = (t<255) ? src[t+1] : 0;
    if (above < k && above + sum >= k){
      int cum = above;
      #pragma unroll
      for (int j=7;j>=0;j--){
        int c = lv[j];
        if (cum + c >= k){ binr[g*2] = t*8 + j; binr[g*2+1] = k - cum; break; }
        cum += c;
      }
    }
  }
}

// fully-parallel pass: sum/count above prefix bin; collect prefix-bin candidates.
// Per-block partials via plain stores (NO float atomics).
__global__ __launch_bounds__(256) void kpassA(
    const float* __restrict__ negvals, const int* __restrict__ binr,
    float* __restrict__ parts2, int* __restrict__ candcnt, float* __restrict__ cand)
{
  const int b = blockIdx.y;
  const int bx = blockIdx.x;
  int s, lb, Nq; size_t segbase;
  if (bx < 75)      { s=0; lb=bx;    Nq=N0/4; segbase=(size_t)b*N0; }
  else if (bx < 94) { s=1; lb=bx-75; Nq=N1/4; segbase=(size_t)BNUM*N0 + (size_t)b*N1; }
  else              { s=2; lb=bx-94; Nq=N2/4; segbase=(size_t)BNUM*(N0+N1) + (size_t)b*N2; }
  const int g = s*BNUM + b;
  const int pbin = binr[g*2];
  const int i = lb*256 + threadIdx.x;
  float sum=0.f, cnt=0.f;
  if (i < Nq){
    const float4 v4 = ((const float4*)(negvals+segbase))[i];
    float vv[4] = {v4.x, v4.y, v4.z, v4.w};
    #pragma unroll
    for (int j=0;j<4;j++){
      float v = vv[j];
      if (v >= 0.f){
        int vb = (int)(__float_as_uint(v)>>20);
        if (vb > pbin){ sum += v; cnt += 1.f; }
        else if (vb == pbin){
          int idx = atomicAdd(&candcnt[g], 1);   // int atomic: native
          if (idx < CAP) cand[g*CAP + idx] = v;
        }
      }
    }
  }
  __shared__ float red[2][4];
  const int lane = threadIdx.x & 63, wv = threadIdx.x >> 6;
  float r0 = wred(sum), r1 = wred(cnt);
  if (lane==0){ red[0][wv]=r0; red[1][wv]=r1; }
  __syncthreads();
  if (threadIdx.x==0){
    float* pg = parts2 + (size_t)(g*75 + lb)*2;
    pg[0] = red[0][0]+red[0][1]+red[0][2]+red[0][3];
    pg[1] = red[1][0]+red[1][1]+red[1][2]+red[1][3];
  }
}

// 96 blocks: reduce kpassA partials; exact rank among candidates -> thr -> per-(b,s) losses
__global__ __launch_bounds__(256) void krank(
    const float* __restrict__ acc, const float* __restrict__ parts2,
    const int* __restrict__ candcnt, const float* __restrict__ cand,
    const int* __restrict__ binr, float* __restrict__ gl)
{
  const int g = blockIdx.x;
  const int t = threadIdx.x;
  const int s = g >> 5;
  const int nb2 = (s==0)?75:((s==1)?19:5);
  __shared__ float sc[CAP];
  __shared__ float s_thr;

  float asum=0.f, acnt=0.f;
  if (t < nb2){
    const float* pg = parts2 + (size_t)(g*75 + t)*2;
    asum = pg[0]; acnt = pg[1];
  }

  const float nposf = acc[g*5+0], availf = acc[g*5+1];
  const int npos = (int)(nposf+0.5f), avail = (int)(availf+0.5f);
  const int k = (npos==0) ? (avail<100?avail:100) : (3*npos<avail?3*npos:avail);
  float selS=0.f, selC=0.f;
  if (k > 0){
    const int m = min(candcnt[g], CAP);
    const int r = binr[g*2+1];
    if (t==0) s_thr = INFINITY;
    for (int i=t; i<m; i+=256) sc[i] = cand[g*CAP + i];
    __syncthreads();
    for (int i=t; i<m; i+=256){
      float v = sc[i]; int gt=0, ge=0;
      for (int j=0;j<m;j++){ float w2 = sc[j]; gt += (w2>v)?1:0; ge += (w2>=v)?1:0; }
      if (gt < r && ge >= r) s_thr = v;   // unique by value
    }
    __syncthreads();
    const float thr = s_thr;
    for (int i=t; i<m; i+=256){ float v = sc[i]; if (v >= thr){ selS += v; selC += 1.f; } }
  }
  __shared__ float red[2][4];
  const int lane = t & 63, wv = t >> 6;
  float r0 = wred(asum + selS), r1 = wred(acnt + selC);
  if (lane==0){ red[0][wv]=r0; red[1][wv]=r1; }
  __syncthreads();
  if (t==0){
    float ss = red[0][0]+red[0][1]+red[0][2]+red[0][3];
    float ns = red[1][0]+red[1][1]+red[1][2]+red[1][3];
    float totS = ss + acc[g*5+2];
    float totC = ns + nposf;
    gl[g*3+0] = (totC > 0.f) ? totS/totC : 0.f;
    gl[g*3+1] = (npos > 0) ? acc[g*5+3]/nposf : 0.f;
    gl[g*3+2] = (npos > 0) ? acc[g*5+4]/(nposf*4.f) : 0.f;
  }
}

__global__ __launch_bounds__(256) void kfin(const float* __restrict__ gl, float* __restrict__ out){
  const int t = threadIdx.x;
  float lo=0.f, lc=0.f, ll=0.f;
  if (t < 96){ lo=gl[t*3]; lc=gl[t*3+1]; ll=gl[t*3+2]; }
  __shared__ float red[3][4];
  const int lane = t & 63, wv = t >> 6;
  float r0=wred(lo), r1=wred(lc), r2=wred(ll);
  if (lane==0){ red[0][wv]=r0; red[1][wv]=r1; red[2][wv]=r2; }
  __syncthreads();
  if (t==0){
    float a = (red[0][0]+red[0][1]+red[0][2]+red[0][3])*(1.f/32.f);
    float b = (red[1][0]+red[1][1]+red[1][2]+red[1][3])*(1.f/32.f);
    float c = (red[2][0]+red[2][1]+red[2][2]+red[2][3])*(1.f/32.f);
    out[0]=a; out[1]=b; out[2]=c; out[3]=a+b+c;
  }
}

extern "C" void kernel_launch(void* const* d_in, const int* in_sizes, int n_in,
                              void* d_out, int out_size, void* d_ws, size_t ws_size,
                              hipStream_t stream)
{
  const float* p0 = (const float*)d_in[0];
  const float* p1 = (const float*)d_in[1];
  const float* p2 = (const float*)d_in[2];
  const float* boxes  = (const float*)d_in[6];
  const int*   labels = (const int*)d_in[7];
  float* out = (float*)d_out;

  float* negvals = (float*)d_ws;                    // 3,225,600 f
  int*   hist    = (int*)(negvals + 3225600);       // 96*2048 (zeroed)
  int*   candcnt = hist + 96*NBIN;                  // 96 (zeroed)
  float* acc     = (float*)(candcnt + 96);          // 480
  int*   binr    = (int*)(acc + 480);               // 192
  // scratch region: part (k1->kfindbin) then reused by cand (kpassA->krank)
  float* part    = (float*)(binr + 192);            // 48,000 (dead after kfindbin)
  float* cand    = part;                            // 96*2048 (alias, used after part dead)
  float* parts2  = cand + 96*CAP;                   // 96*75*2
  float* gl      = parts2 + 14400;                  // 288

  kzero<<<(ZLEN+255)/256, 256, 0, stream>>>(hist);
  k1<<<dim3(132,32), 256, 0, stream>>>(p0,p1,p2,boxes,labels,negvals,hist,part);
  kfindbin<<<96, 256, 0, stream>>>(hist, part, acc, binr);
  kpassA<<<dim3(99,32), 256, 0, stream>>>(negvals, binr, parts2, candcnt, cand);
  krank<<<96, 256, 0, stream>>>(acc, parts2, candcnt, cand, binr, gl);
  kfin<<<1, 256, 0, stream>>>(gl, out);
}

// Round 4
// 706.022 us; speedup vs baseline: 1.0165x; 1.0078x over previous
//
#include <hip/hip_runtime.h>
#include <math.h>

#define ANUM 3
#define BNUM 32
#define NBIN 2048
#define CAP  2048
#define N0 76800
#define N1 19200
#define N2 4800
#define ZLEN (96*NBIN + 96)   // hist + candcnt (ints)

// ---- device-resident scratch (VRAM; d_ws appears to be host-pinned => avoid it) ----
__device__ float g_negvals[BNUM*(N0+N1+N2)];   // 12.9 MB
__device__ int   g_hist[96*NBIN];              // 786 KB
__device__ int   g_candcnt[96];
__device__ float g_acc[480];
__device__ int   g_binr[192];
__device__ float g_part[96*100*5];
__device__ float g_cand[96*CAP];
__device__ float g_parts2[96*75*2];
__device__ float g_gl[288];

__device__ __forceinline__ float wred(float v){
  #pragma unroll
  for (int off=32; off; off>>=1) v += __shfl_down(v, off, 64);
  return v;
}

__global__ __launch_bounds__(256) void kzero(){
  int i = blockIdx.x*256 + threadIdx.x;
  if (i < 96*NBIN) g_hist[i] = 0;
  if (i < 96) g_candcnt[i] = 0;
}

// One thread per pixel, 3 anchors per thread. All 3 scales in one launch.
__global__ __launch_bounds__(256) void k1(
    const float* __restrict__ p0, const float* __restrict__ p1, const float* __restrict__ p2,
    const float* __restrict__ boxes, const int* __restrict__ labels)
{
  const int b = blockIdx.y;
  const int bx = blockIdx.x;
  int s, lb, W, HW; const float* __restrict__ pred; size_t segbase;
  if (bx < 100)      { s=0; lb=bx;     W=160; HW=25600; pred=p0; segbase=(size_t)b*N0; }
  else if (bx < 125) { s=1; lb=bx-100; W=80;  HW=6400;  pred=p1; segbase=(size_t)BNUM*N0 + (size_t)b*N1; }
  else               { s=2; lb=bx-125; W=40;  HW=1600;  pred=p2; segbase=(size_t)BNUM*(N0+N1) + (size_t)b*N2; }
  const int g = s*BNUM + b;

  __shared__ float sraw[64];
  __shared__ float scor[16][5];
  __shared__ int   slab[16];
  __shared__ int   shist[NBIN];

  #pragma unroll
  for (int j=0;j<NBIN/256;j++) shist[threadIdx.x + j*256] = 0;
  if (threadIdx.x < 64) sraw[threadIdx.x] = boxes[b*64 + threadIdx.x];
  else if (threadIdx.x < 80) slab[threadIdx.x-64] = labels[b*16 + threadIdx.x - 64];
  __syncthreads();
  if (threadIdx.x < 16){
    float bcx=sraw[4*threadIdx.x], bcy=sraw[4*threadIdx.x+1];
    float bw =sraw[4*threadIdx.x+2], bh=sraw[4*threadIdx.x+3];
    float x0=bcx-bw*0.5f, y0=bcy-bh*0.5f, x1=bcx+bw*0.5f, y1=bcy+bh*0.5f;
    scor[threadIdx.x][0]=x0; scor[threadIdx.x][1]=y0;
    scor[threadIdx.x][2]=x1; scor[threadIdx.x][3]=y1;
    scor[threadIdx.x][4]=(x1-x0)*(y1-y0);
  }
  __syncthreads();

  const int pix = lb*256 + threadIdx.x;
  float f_pos=0.f, f_neg=0.f, f_obj=0.f, f_ce=0.f, f_sl1=0.f;

  if (pix < HW){
    const int h = pix / W;
    const int w = pix - h*W;
    const float fw = (float)W;  // H == W for all scales
    const float cx = ((float)w + 0.5f)/fw;
    const float cy = ((float)h + 0.5f)/fw;
    const float* pb = pred + (size_t)b*24*HW;

    #pragma unroll
    for (int a=0;a<ANUM;a++){
      const float sz = (a==0)?0.08f:((a==1)?0.16f:0.28f);
      const float hs = sz*0.5f;
      const float ax0=cx-hs, ay0=cy-hs, ax1=cx+hs, ay1=cy+hs;
      const float areaA=(ax1-ax0)*(ay1-ay0);
      float best=-1.f; int midx=0;
      #pragma unroll
      for (int m=0;m<16;m++){
        float iw=fminf(ax1,scor[m][2])-fmaxf(ax0,scor[m][0]);
        float ih=fminf(ay1,scor[m][3])-fmaxf(ay0,scor[m][1]);
        iw=fmaxf(iw,0.f); ih=fmaxf(ih,0.f);
        float inter=iw*ih;
        float iou=inter/(areaA+scor[m][4]-inter+1e-9f);
        if (iou>best){best=iou; midx=m;}
      }
      const bool pos = best>=0.5f;
      const bool neg = best<0.4f;
      const float obj = pb[(a*8+4)*HW + pix];
      const float sp = log1pf(expf(-fabsf(obj)));
      const float obj_all = fmaxf(obj,0.f) - (pos?obj:0.f) + sp;
      g_negvals[segbase + a*HW + pix] = neg ? obj_all : -1.f;
      if (neg){
        f_neg += 1.f;
        atomicAdd(&shist[__float_as_uint(obj_all)>>20], 1);   // LDS int atomic
      } else if (pos){
        f_pos += 1.f; f_obj += obj_all;
        float c0=pb[(a*8+5)*HW+pix], c1=pb[(a*8+6)*HW+pix], c2=pb[(a*8+7)*HW+pix];
        float mx=fmaxf(c0,fmaxf(c1,c2));
        float lse=mx+logf(expf(c0-mx)+expf(c1-mx)+expf(c2-mx));
        int ct=slab[midx]-1; ct = ct<0?0:(ct>2?2:ct);
        float csel=(ct==0)?c0:((ct==1)?c1:c2);
        f_ce += lse-csel;
        float mcx=sraw[4*midx],mcy=sraw[4*midx+1],mw=sraw[4*midx+2],mh=sraw[4*midx+3];
        float t0=(mcx-cx)/sz, t1=(mcy-cy)/sz, t2=logf(mw/sz), t3=logf(mh/sz);
        float l0=pb[(a*8+0)*HW+pix], l1=pb[(a*8+1)*HW+pix];
        float l2=pb[(a*8+2)*HW+pix], l3=pb[(a*8+3)*HW+pix];
        float d, ssm=0.f;
        d=fabsf(l0-t0); ssm += (d<1.f)?(0.5f*d*d):(d-0.5f);
        d=fabsf(l1-t1); ssm += (d<1.f)?(0.5f*d*d):(d-0.5f);
        d=fabsf(l2-t2); ssm += (d<1.f)?(0.5f*d*d):(d-0.5f);
        d=fabsf(l3-t3); ssm += (d<1.f)?(0.5f*d*d):(d-0.5f);
        f_sl1 += ssm;
      }
    }
  }

  __syncthreads();
  // flush LDS hist (sparse); int atomics are native RMW in VRAM L2
  #pragma unroll
  for (int j=0;j<NBIN/256;j++){
    int bin = threadIdx.x + j*256;
    int c = shist[bin];
    if (c) atomicAdd(&g_hist[g*NBIN + bin], c);
  }

  __shared__ float red[5][4];
  const int lane = threadIdx.x & 63, wv = threadIdx.x >> 6;
  float vals[5] = {f_pos, f_neg, f_obj, f_ce, f_sl1};
  #pragma unroll
  for (int q=0;q<5;q++){
    float r = wred(vals[q]);
    if (lane==0) red[q][wv] = r;
  }
  __syncthreads();
  if (threadIdx.x==0){
    float* pg = g_part + (size_t)(g*100 + lb)*5;
    #pragma unroll
    for (int q=0;q<5;q++)
      pg[q] = red[q][0]+red[q][1]+red[q][2]+red[q][3];
  }
}

// 96 blocks: reduce k1 partials -> acc; suffix-scan 2048 bins -> prefix bin + rank
__global__ __launch_bounds__(256) void kfindbin(){
  const int g = blockIdx.x;
  const int t = threadIdx.x;
  const int s = g >> 5;
  const int nb = (s==0)?100:((s==1)?25:7);

  const int4* h4 = (const int4*)(g_hist + g*NBIN);
  int4 v0 = h4[t*2+0], v1 = h4[t*2+1];
  int lv[8] = {v0.x,v0.y,v0.z,v0.w, v1.x,v1.y,v1.z,v1.w};
  int sum = 0;
  #pragma unroll
  for (int j=0;j<8;j++) sum += lv[j];

  // reduce per-block partials
  float pv[5] = {0.f,0.f,0.f,0.f,0.f};
  if (t < nb){
    const float* pg = g_part + (size_t)(g*100 + t)*5;
    #pragma unroll
    for (int q=0;q<5;q++) pv[q] = pg[q];
  }
  __shared__ float red[5][4];
  __shared__ int s_k;
  const int lane = t & 63, wv = t >> 6;
  #pragma unroll
  for (int q=0;q<5;q++){
    float r = wred(pv[q]);
    if (lane==0) red[q][wv] = r;
  }
  __syncthreads();
  if (t==0){
    float tot[5];
    #pragma unroll
    for (int q=0;q<5;q++){
      tot[q] = red[q][0]+red[q][1]+red[q][2]+red[q][3];
      g_acc[g*5+q] = tot[q];
    }
    const int npos = (int)(tot[0]+0.5f), avail = (int)(tot[1]+0.5f);
    int k = (npos==0) ? (avail<100?avail:100) : (3*npos<avail?3*npos:avail);
    s_k = k;
    if (k<=0){ g_binr[g*2]=NBIN; g_binr[g*2+1]=0; }
  }
  __syncthreads();
  const int k = s_k;

  __shared__ int sa[256], sb[256];
  sa[t] = sum; __syncthreads();
  int* src = sa; int* dst = sb;
  #pragma unroll
  for (int st=1; st<256; st<<=1){
    int v = src[t] + ((t+st<256)? src[t+st] : 0);
    dst[t] = v; __syncthreads();
    int* tmp = src; src = dst; dst = tmp;
  }
  // src[t] = inclusive suffix sum over thread chunks t..255
  if (k>0){
    int above = (t<255) ? src[t+1] : 0;
    if (above < k && above + sum >= k){
      int cum = above;
      #pragma unroll
      for (int j=7;j>=0;j--){
        int c = lv[j];
        if (cum + c >= k){ g_binr[g*2] = t*8 + j; g_binr[g*2+1] = k - cum; break; }
        cum += c;
      }
    }
  }
}

// fully-parallel pass: sum/count above prefix bin; collect prefix-bin candidates.
__global__ __launch_bounds__(256) void kpassA(){
  const int b = blockIdx.y;
  const int bx = blockIdx.x;
  int s, lb, Nq; size_t segbase;
  if (bx < 75)      { s=0; lb=bx;    Nq=N0/4; segbase=(size_t)b*N0; }
  else if (bx < 94) { s=1; lb=bx-75; Nq=N1/4; segbase=(size_t)BNUM*N0 + (size_t)b*N1; }
  else              { s=2; lb=bx-94; Nq=N2/4; segbase=(size_t)BNUM*(N0+N1) + (size_t)b*N2; }
  const int g = s*BNUM + b;
  const int pbin = g_binr[g*2];
  const int i = lb*256 + threadIdx.x;
  float sum=0.f, cnt=0.f;
  if (i < Nq){
    const float4 v4 = ((const float4*)(g_negvals+segbase))[i];
    float vv[4] = {v4.x, v4.y, v4.z, v4.w};
    #pragma unroll
    for (int j=0;j<4;j++){
      float v = vv[j];
      if (v >= 0.f){
        int vb = (int)(__float_as_uint(v)>>20);
        if (vb > pbin){ sum += v; cnt += 1.f; }
        else if (vb == pbin){
          int idx = atomicAdd(&g_candcnt[g], 1);   // int atomic
          if (idx < CAP) g_cand[g*CAP + idx] = v;
        }
      }
    }
  }
  __shared__ float red[2][4];
  const int lane = threadIdx.x & 63, wv = threadIdx.x >> 6;
  float r0 = wred(sum), r1 = wred(cnt);
  if (lane==0){ red[0][wv]=r0; red[1][wv]=r1; }
  __syncthreads();
  if (threadIdx.x==0){
    float* pg = g_parts2 + (size_t)(g*75 + lb)*2;
    pg[0] = red[0][0]+red[0][1]+red[0][2]+red[0][3];
    pg[1] = red[1][0]+red[1][1]+red[1][2]+red[1][3];
  }
}

// 96 blocks: reduce kpassA partials; exact rank among candidates -> thr -> per-(b,s) losses
__global__ __launch_bounds__(256) void krank(){
  const int g = blockIdx.x;
  const int t = threadIdx.x;
  const int s = g >> 5;
  const int nb2 = (s==0)?75:((s==1)?19:5);
  __shared__ float sc[CAP];
  __shared__ float s_thr;

  float asum=0.f, acnt=0.f;
  if (t < nb2){
    const float* pg = g_parts2 + (size_t)(g*75 + t)*2;
    asum = pg[0]; acnt = pg[1];
  }

  const float nposf = g_acc[g*5+0], availf = g_acc[g*5+1];
  const int npos = (int)(nposf+0.5f), avail = (int)(availf+0.5f);
  const int k = (npos==0) ? (avail<100?avail:100) : (3*npos<avail?3*npos:avail);
  float selS=0.f, selC=0.f;
  if (k > 0){
    const int m = min(g_candcnt[g], CAP);
    const int r = g_binr[g*2+1];
    if (t==0) s_thr = INFINITY;
    for (int i=t; i<m; i+=256) sc[i] = g_cand[g*CAP + i];
    __syncthreads();
    for (int i=t; i<m; i+=256){
      float v = sc[i]; int gt=0, ge=0;
      for (int j=0;j<m;j++){ float w2 = sc[j]; gt += (w2>v)?1:0; ge += (w2>=v)?1:0; }
      if (gt < r && ge >= r) s_thr = v;   // unique by value
    }
    __syncthreads();
    const float thr = s_thr;
    for (int i=t; i<m; i+=256){ float v = sc[i]; if (v >= thr){ selS += v; selC += 1.f; } }
  }
  __shared__ float red[2][4];
  const int lane = t & 63, wv = t >> 6;
  float r0 = wred(asum + selS), r1 = wred(acnt + selC);
  if (lane==0){ red[0][wv]=r0; red[1][wv]=r1; }
  __syncthreads();
  if (t==0){
    float ss = red[0][0]+red[0][1]+red[0][2]+red[0][3];
    float ns = red[1][0]+red[1][1]+red[1][2]+red[1][3];
    float totS = ss + g_acc[g*5+2];
    float totC = ns + nposf;
    g_gl[g*3+0] = (totC > 0.f) ? totS/totC : 0.f;
    g_gl[g*3+1] = (npos > 0) ? g_acc[g*5+3]/nposf : 0.f;
    g_gl[g*3+2] = (npos > 0) ? g_acc[g*5+4]/(nposf*4.f) : 0.f;
  }
}

__global__ __launch_bounds__(256) void kfin(float* __restrict__ out){
  const int t = threadIdx.x;
  float lo=0.f, lc=0.f, ll=0.f;
  if (t < 96){ lo=g_gl[t*3]; lc=g_gl[t*3+1]; ll=g_gl[t*3+2]; }
  __shared__ float red[3][4];
  const int lane = t & 63, wv = t >> 6;
  float r0=wred(lo), r1=wred(lc), r2=wred(ll);
  if (lane==0){ red[0][wv]=r0; red[1][wv]=r1; red[2][wv]=r2; }
  __syncthreads();
  if (t==0){
    float a = (red[0][0]+red[0][1]+red[0][2]+red[0][3])*(1.f/32.f);
    float b = (red[1][0]+red[1][1]+red[1][2]+red[1][3])*(1.f/32.f);
    float c = (red[2][0]+red[2][1]+red[2][2]+red[2][3])*(1.f/32.f);
    out[0]=a; out[1]=b; out[2]=c; out[3]=a+b+c;
  }
}

extern "C" void kernel_launch(void* const* d_in, const int* in_sizes, int n_in,
                              void* d_out, int out_size, void* d_ws, size_t ws_size,
                              hipStream_t stream)
{
  const float* p0 = (const float*)d_in[0];
  const float* p1 = (const float*)d_in[1];
  const float* p2 = (const float*)d_in[2];
  const float* boxes  = (const float*)d_in[6];
  const int*   labels = (const int*)d_in[7];
  float* out = (float*)d_out;

  kzero<<<(ZLEN+255)/256, 256, 0, stream>>>();
  k1<<<dim3(132,32), 256, 0, stream>>>(p0,p1,p2,boxes,labels);
  kfindbin<<<96, 256, 0, stream>>>();
  kpassA<<<dim3(99,32), 256, 0, stream>>>();
  krank<<<96, 256, 0, stream>>>();
  kfin<<<1, 256, 0, stream>>>(out);
}